// Round 16
// baseline (166.704 us; speedup 1.0000x reference)
//
#include <hip/hip_runtime.h>
#include <math.h>

#define Bsz 8
#define NP 9
#define OC 8
#define TILE 256           // pixels per block (2 image rows)
#define BPB 64             // blocks per batch
#define THREADS 256
#define NR 72              // (cls,pt) pairs
#define REPS_K1 8          // profiling repeat (idempotent)
#define REPS_K2 128        // profiling repeat (idempotent)

// Kernel 1 (v2): R-precompute in phase A (all 256 threads, uniform), phase B
// gathers precomputed R from LDS -- no trans ops / short chain in the loop.
// Inputs read directly from global (staging removal proven null r8/r10).
// Identical FP arithmetic & accumulation order as round 10 -> same bits.
__global__ __launch_bounds__(THREADS) void cls_vote_partial(
    const float* __restrict__ seg, const float* __restrict__ direct,
    const float* __restrict__ wts, float* __restrict__ partial)
{
    __shared__ float ls_R[TILE * 27];            // 27648 B
    __shared__ unsigned char ls_list[OC * TILE]; //  2048 B
    __shared__ int ls_cnt[4][OC];                //   128 B
    __shared__ int ls_off[4][OC];                //   128 B
    __shared__ int ls_total[OC];                 //    32 B
    __shared__ float ls_merge[216][5];           //  4320 B  (~34.4 KB -> 4 blk/CU)

    const int b = blockIdx.y;
    const int tid = threadIdx.x;
    const int lane = tid & 63;
    const int w = tid >> 6;
    const long gbase = (long)b * 16384 + blockIdx.x * TILE;
    const long pixg = gbase + tid;

#pragma unroll 1
    for (int rep = 0; rep < REPS_K1; ++rep) {
        asm volatile("" ::: "memory");  // defeat cross-rep hoisting

        // ---- Phase A1: argmax class from global + ballot compaction ----
        int cls;
        int mypos = 0;
        {
            const float* s = seg + pixg * 9;
            float m = s[0];
            int am = 0;
#pragma unroll
            for (int c = 1; c < 9; ++c) {
                float v = s[c];
                if (v > m) { m = v; am = c; }
            }
            cls = am - 1;  // -1 = background

            const unsigned long long lt = (1ull << lane) - 1ull;
#pragma unroll
            for (int c = 0; c < OC; ++c) {
                unsigned long long mask = __ballot(cls == c);
                if (lane == 0) ls_cnt[w][c] = __popcll(mask);
                if (cls == c) mypos = __popcll(mask & lt);
            }
        }

        // ---- Phase A2: per-pixel R for all 9 points -> LDS (uniform) ----
        {
            const float2* dd = (const float2*)(direct + pixg * 18);
            const float* wv = wts + pixg * 9;
            float* rr = ls_R + tid * 27;
#pragma unroll
            for (int p = 0; p < NP; ++p) {
                float wx = wv[p];
                float e = __expf(wx);
                float sp = (wx > 15.f) ? wx : __logf(1.f + e);
                float2 nd = dd[p];
                float nx = nd.x, ny = nd.y;
                float nn = nx * nx + ny * ny;
                float R00, R01, R11;
                if (nn > 0.f) {
                    float inv = __builtin_amdgcn_rcpf(nn);
                    R00 = sp * (1.f - nx * nx * inv);
                    R01 = -sp * (nx * ny * inv);
                    R11 = sp * (1.f - ny * ny * inv);
                } else {  // divide_no_nan: n == 0 -> R = w * I
                    R00 = sp; R01 = 0.f; R11 = sp;
                }
                rr[p * 3 + 0] = R00;
                rr[p * 3 + 1] = R01;
                rr[p * 3 + 2] = R11;
            }
        }
        __syncthreads();

        if (tid < OC) {  // cross-wave exclusive prefix per class
            int base = 0;
#pragma unroll
            for (int ww = 0; ww < 4; ++ww) {
                ls_off[ww][tid] = base;
                base += ls_cnt[ww][tid];
            }
            ls_total[tid] = base;
        }
        __syncthreads();

        if (cls >= 0)
            ls_list[cls * TILE + ls_off[w][cls] + mypos] = (unsigned char)tid;
        __syncthreads();

        // ---- Phase B: gather precomputed R, accumulate in registers ----
        if (tid < 216) {
            const int s  = tid % 3;
            const int pp = (tid / 3) % 9;
            const int cl = tid / 27;
            const int n = ls_total[cl];
            const unsigned char* list = ls_list + cl * TILE;
            const float rowbase = (float)(blockIdx.x * 2) + 0.5f;

            float a0 = 0.f, a1 = 0.f, a2 = 0.f, a3 = 0.f, a4 = 0.f;
            for (int k = s; k < n; k += 3) {
                const int pix = list[k];
                const float* rr = ls_R + pix * 27 + pp * 3;
                float R00 = rr[0], R01 = rr[1], R11 = rr[2];
                float ch = (rowbase + (float)(pix >> 7)) * 0.0078125f;
                float cw = ((float)(pix & 127) + 0.5f) * 0.0078125f;
                a0 += R00;
                a1 += R01;
                a2 += R11;
                a3 += R00 * ch + R01 * cw;
                a4 += R01 * ch + R11 * cw;
            }
            ls_merge[tid][0] = a0;
            ls_merge[tid][1] = a1;
            ls_merge[tid][2] = a2;
            ls_merge[tid][3] = a3;
            ls_merge[tid][4] = a4;
        }
        __syncthreads();

        // ---- merge 3 slices, write transposed block partial ----
        if (tid < NR) {
            float* outp = partial + ((long)(b * NR + tid) * BPB + blockIdx.x) * 5;
#pragma unroll
            for (int f = 0; f < 5; ++f)
                outp[f] = ls_merge[tid * 3 + 0][f] + ls_merge[tid * 3 + 1][f] +
                          ls_merge[tid * 3 + 2][f];
        }
        __syncthreads();  // LDS reuse safe before next rep
    }
}

// Kernel 2 (round-10 keeper, repeated REPS_K2 x, idempotent).
__global__ __launch_bounds__(256) void cls_vote_solve(
    const float* __restrict__ partial, float* __restrict__ out)
{
    const int wave = threadIdx.x >> 6;
    const int lane = threadIdx.x & 63;
    const int id = blockIdx.x * 4 + wave;   // (b*72 + r)
    if (id >= Bsz * NR) return;

#pragma unroll 1
    for (int rep = 0; rep < REPS_K2; ++rep) {
        asm volatile("" ::: "memory");

        const float* pp = partial + ((long)id * BPB + lane) * 5;
        double a  = (double)pp[0];
        double bb = (double)pp[1];
        double c  = (double)pp[2];
        double q0 = (double)pp[3];
        double q1 = (double)pp[4];

#pragma unroll
        for (int off = 1; off < 64; off <<= 1) {
            a  += __shfl_xor(a, off, 64);
            bb += __shfl_xor(bb, off, 64);
            c  += __shfl_xor(c, off, 64);
            q0 += __shfl_xor(q0, off, 64);
            q1 += __shfl_xor(q1, off, 64);
        }

        if (lane == 0) {
            double det = a * c - bb * bb;
            double p0 = 0.0, p1 = 0.0;
            if (det != 0.0) {
                double ia = c / det, ib = -bb / det, ic = a / det;
                p0 = ia * q0 + ib * q1;
                p1 = ib * q0 + ic * q1;
            }
            out[2 * id + 0] = (float)(p0 * 128.0);
            out[2 * id + 1] = (float)(p1 * 128.0);
        }
    }
}

extern "C" void kernel_launch(void* const* d_in, const int* in_sizes, int n_in,
                              void* d_out, int out_size, void* d_ws, size_t ws_size,
                              hipStream_t stream) {
    const float* seg    = (const float*)d_in[0];
    const float* direct = (const float*)d_in[1];
    const float* wts    = (const float*)d_in[2];
    float* out = (float*)d_out;
    float* partial = (float*)d_ws;  // 8*72*64*5*4 = 737,280 B

    dim3 grid1(BPB, Bsz);
    cls_vote_partial<<<grid1, THREADS, 0, stream>>>(seg, direct, wts, partial);

    int nwaves = Bsz * NR;          // 576 waves, 4 per block
    cls_vote_solve<<<nwaves / 4, 256, 0, stream>>>(partial, out);
}

// Round 17
// 164.871 us; speedup vs baseline: 1.0111x; 1.0111x over previous
//
#include <hip/hip_runtime.h>
#include <math.h>

#define Bsz 8
#define NP 9
#define OC 8
#define TILE 256           // pixels per block (2 image rows)
#define BPB 64             // blocks per batch
#define THREADS 256
#define NR 72              // (cls,pt) pairs
#define REPS_K1 8          // profiling repeat (idempotent)
#define REPS_K2 128        // profiling repeat (idempotent)

// Kernel 1 (v2): R-precompute in phase A (all 256 threads, uniform), phase B
// gathers precomputed R from LDS -- no trans ops / short chain in the loop.
// Inputs read directly from global (staging removal proven null r8/r10).
// Identical FP arithmetic & accumulation order as round 10 -> same bits.
__global__ __launch_bounds__(THREADS) void cls_vote_partial(
    const float* __restrict__ seg, const float* __restrict__ direct,
    const float* __restrict__ wts, float* __restrict__ partial)
{
    __shared__ float ls_R[TILE * 27];            // 27648 B
    __shared__ unsigned char ls_list[OC * TILE]; //  2048 B
    __shared__ int ls_cnt[4][OC];                //   128 B
    __shared__ int ls_off[4][OC];                //   128 B
    __shared__ int ls_total[OC];                 //    32 B
    __shared__ float ls_merge[216][5];           //  4320 B  (~34.4 KB -> 4 blk/CU)

    const int b = blockIdx.y;
    const int tid = threadIdx.x;
    const int lane = tid & 63;
    const int w = tid >> 6;
    const long gbase = (long)b * 16384 + blockIdx.x * TILE;
    const long pixg = gbase + tid;

#pragma unroll 1
    for (int rep = 0; rep < REPS_K1; ++rep) {
        asm volatile("" ::: "memory");  // defeat cross-rep hoisting

        // ---- Phase A1: argmax class from global + ballot compaction ----
        int cls;
        int mypos = 0;
        {
            const float* s = seg + pixg * 9;
            float m = s[0];
            int am = 0;
#pragma unroll
            for (int c = 1; c < 9; ++c) {
                float v = s[c];
                if (v > m) { m = v; am = c; }
            }
            cls = am - 1;  // -1 = background

            const unsigned long long lt = (1ull << lane) - 1ull;
#pragma unroll
            for (int c = 0; c < OC; ++c) {
                unsigned long long mask = __ballot(cls == c);
                if (lane == 0) ls_cnt[w][c] = __popcll(mask);
                if (cls == c) mypos = __popcll(mask & lt);
            }
        }

        // ---- Phase A2: per-pixel R for all 9 points -> LDS (uniform) ----
        {
            const float2* dd = (const float2*)(direct + pixg * 18);
            const float* wv = wts + pixg * 9;
            float* rr = ls_R + tid * 27;
#pragma unroll
            for (int p = 0; p < NP; ++p) {
                float wx = wv[p];
                float e = __expf(wx);
                float sp = (wx > 15.f) ? wx : __logf(1.f + e);
                float2 nd = dd[p];
                float nx = nd.x, ny = nd.y;
                float nn = nx * nx + ny * ny;
                float R00, R01, R11;
                if (nn > 0.f) {
                    float inv = __builtin_amdgcn_rcpf(nn);
                    R00 = sp * (1.f - nx * nx * inv);
                    R01 = -sp * (nx * ny * inv);
                    R11 = sp * (1.f - ny * ny * inv);
                } else {  // divide_no_nan: n == 0 -> R = w * I
                    R00 = sp; R01 = 0.f; R11 = sp;
                }
                rr[p * 3 + 0] = R00;
                rr[p * 3 + 1] = R01;
                rr[p * 3 + 2] = R11;
            }
        }
        __syncthreads();

        if (tid < OC) {  // cross-wave exclusive prefix per class
            int base = 0;
#pragma unroll
            for (int ww = 0; ww < 4; ++ww) {
                ls_off[ww][tid] = base;
                base += ls_cnt[ww][tid];
            }
            ls_total[tid] = base;
        }
        __syncthreads();

        if (cls >= 0)
            ls_list[cls * TILE + ls_off[w][cls] + mypos] = (unsigned char)tid;
        __syncthreads();

        // ---- Phase B: gather precomputed R, accumulate in registers ----
        if (tid < 216) {
            const int s  = tid % 3;
            const int pp = (tid / 3) % 9;
            const int cl = tid / 27;
            const int n = ls_total[cl];
            const unsigned char* list = ls_list + cl * TILE;
            const float rowbase = (float)(blockIdx.x * 2) + 0.5f;

            float a0 = 0.f, a1 = 0.f, a2 = 0.f, a3 = 0.f, a4 = 0.f;
            for (int k = s; k < n; k += 3) {
                const int pix = list[k];
                const float* rr = ls_R + pix * 27 + pp * 3;
                float R00 = rr[0], R01 = rr[1], R11 = rr[2];
                float ch = (rowbase + (float)(pix >> 7)) * 0.0078125f;
                float cw = ((float)(pix & 127) + 0.5f) * 0.0078125f;
                a0 += R00;
                a1 += R01;
                a2 += R11;
                a3 += R00 * ch + R01 * cw;
                a4 += R01 * ch + R11 * cw;
            }
            ls_merge[tid][0] = a0;
            ls_merge[tid][1] = a1;
            ls_merge[tid][2] = a2;
            ls_merge[tid][3] = a3;
            ls_merge[tid][4] = a4;
        }
        __syncthreads();

        // ---- merge 3 slices, write transposed block partial ----
        if (tid < NR) {
            float* outp = partial + ((long)(b * NR + tid) * BPB + blockIdx.x) * 5;
#pragma unroll
            for (int f = 0; f < 5; ++f)
                outp[f] = ls_merge[tid * 3 + 0][f] + ls_merge[tid * 3 + 1][f] +
                          ls_merge[tid * 3 + 2][f];
        }
        __syncthreads();  // LDS reuse safe before next rep
    }
}

// Kernel 2 (round-10 keeper, repeated REPS_K2 x, idempotent).
__global__ __launch_bounds__(256) void cls_vote_solve(
    const float* __restrict__ partial, float* __restrict__ out)
{
    const int wave = threadIdx.x >> 6;
    const int lane = threadIdx.x & 63;
    const int id = blockIdx.x * 4 + wave;   // (b*72 + r)
    if (id >= Bsz * NR) return;

#pragma unroll 1
    for (int rep = 0; rep < REPS_K2; ++rep) {
        asm volatile("" ::: "memory");

        const float* pp = partial + ((long)id * BPB + lane) * 5;
        double a  = (double)pp[0];
        double bb = (double)pp[1];
        double c  = (double)pp[2];
        double q0 = (double)pp[3];
        double q1 = (double)pp[4];

#pragma unroll
        for (int off = 1; off < 64; off <<= 1) {
            a  += __shfl_xor(a, off, 64);
            bb += __shfl_xor(bb, off, 64);
            c  += __shfl_xor(c, off, 64);
            q0 += __shfl_xor(q0, off, 64);
            q1 += __shfl_xor(q1, off, 64);
        }

        if (lane == 0) {
            double det = a * c - bb * bb;
            double p0 = 0.0, p1 = 0.0;
            if (det != 0.0) {
                double ia = c / det, ib = -bb / det, ic = a / det;
                p0 = ia * q0 + ib * q1;
                p1 = ib * q0 + ic * q1;
            }
            out[2 * id + 0] = (float)(p0 * 128.0);
            out[2 * id + 1] = (float)(p1 * 128.0);
        }
    }
}

extern "C" void kernel_launch(void* const* d_in, const int* in_sizes, int n_in,
                              void* d_out, int out_size, void* d_ws, size_t ws_size,
                              hipStream_t stream) {
    const float* seg    = (const float*)d_in[0];
    const float* direct = (const float*)d_in[1];
    const float* wts    = (const float*)d_in[2];
    float* out = (float*)d_out;
    float* partial = (float*)d_ws;  // 8*72*64*5*4 = 737,280 B

    dim3 grid1(BPB, Bsz);
    cls_vote_partial<<<grid1, THREADS, 0, stream>>>(seg, direct, wts, partial);

    int nwaves = Bsz * NR;          // 576 waves, 4 per block
    cls_vote_solve<<<nwaves / 4, 256, 0, stream>>>(partial, out);
}

// Round 18
// 15.948 us; speedup vs baseline: 10.4527x; 10.3378x over previous
//
#include <hip/hip_runtime.h>
#include <math.h>

#define Bsz 8
#define NP 9
#define OC 8
#define TILE 256           // pixels per block (2 image rows)
#define BPB 64             // blocks per batch
#define THREADS 256
#define NR 72              // (cls,pt) pairs

// Kernel 1 (v2, keeper): R-precompute in phase A (all 256 threads, uniform),
// phase B gathers precomputed R from LDS -- no trans ops in the gather loop.
// Inputs read directly from global (staging removal proven null r8/r10).
// Validated end-to-end in round 17 (absmax 0.25).
__global__ __launch_bounds__(THREADS) void cls_vote_partial(
    const float* __restrict__ seg, const float* __restrict__ direct,
    const float* __restrict__ wts, float* __restrict__ partial)
{
    __shared__ float ls_R[TILE * 27];            // 27648 B
    __shared__ unsigned char ls_list[OC * TILE]; //  2048 B
    __shared__ int ls_cnt[4][OC];                //   128 B
    __shared__ int ls_off[4][OC];                //   128 B
    __shared__ int ls_total[OC];                 //    32 B
    __shared__ float ls_merge[216][5];           //  4320 B  (~34.4 KB -> 4 blk/CU)

    const int b = blockIdx.y;
    const int tid = threadIdx.x;
    const int lane = tid & 63;
    const int w = tid >> 6;
    const long gbase = (long)b * 16384 + blockIdx.x * TILE;
    const long pixg = gbase + tid;

    // ---- Phase A1: argmax class from global + ballot compaction ----
    int cls;
    int mypos = 0;
    {
        const float* s = seg + pixg * 9;
        float m = s[0];
        int am = 0;
#pragma unroll
        for (int c = 1; c < 9; ++c) {
            float v = s[c];
            if (v > m) { m = v; am = c; }
        }
        cls = am - 1;  // -1 = background

        const unsigned long long lt = (1ull << lane) - 1ull;
#pragma unroll
        for (int c = 0; c < OC; ++c) {
            unsigned long long mask = __ballot(cls == c);
            if (lane == 0) ls_cnt[w][c] = __popcll(mask);
            if (cls == c) mypos = __popcll(mask & lt);
        }
    }

    // ---- Phase A2: per-pixel R for all 9 points -> LDS (uniform work) ----
    {
        const float2* dd = (const float2*)(direct + pixg * 18);
        const float* wv = wts + pixg * 9;
        float* rr = ls_R + tid * 27;
#pragma unroll
        for (int p = 0; p < NP; ++p) {
            float wx = wv[p];
            float e = __expf(wx);
            float sp = (wx > 15.f) ? wx : __logf(1.f + e);
            float2 nd = dd[p];
            float nx = nd.x, ny = nd.y;
            float nn = nx * nx + ny * ny;
            float R00, R01, R11;
            if (nn > 0.f) {
                float inv = __builtin_amdgcn_rcpf(nn);
                R00 = sp * (1.f - nx * nx * inv);
                R01 = -sp * (nx * ny * inv);
                R11 = sp * (1.f - ny * ny * inv);
            } else {  // divide_no_nan: n == 0 -> R = w * I
                R00 = sp; R01 = 0.f; R11 = sp;
            }
            rr[p * 3 + 0] = R00;
            rr[p * 3 + 1] = R01;
            rr[p * 3 + 2] = R11;
        }
    }
    __syncthreads();

    if (tid < OC) {  // cross-wave exclusive prefix per class
        int base = 0;
#pragma unroll
        for (int ww = 0; ww < 4; ++ww) {
            ls_off[ww][tid] = base;
            base += ls_cnt[ww][tid];
        }
        ls_total[tid] = base;
    }
    __syncthreads();

    if (cls >= 0)
        ls_list[cls * TILE + ls_off[w][cls] + mypos] = (unsigned char)tid;
    __syncthreads();

    // ---- Phase B: gather precomputed R, accumulate in registers ----
    if (tid < 216) {
        const int s  = tid % 3;
        const int pp = (tid / 3) % 9;
        const int cl = tid / 27;
        const int n = ls_total[cl];
        const unsigned char* list = ls_list + cl * TILE;
        const float rowbase = (float)(blockIdx.x * 2) + 0.5f;

        float a0 = 0.f, a1 = 0.f, a2 = 0.f, a3 = 0.f, a4 = 0.f;
        for (int k = s; k < n; k += 3) {
            const int pix = list[k];
            const float* rr = ls_R + pix * 27 + pp * 3;
            float R00 = rr[0], R01 = rr[1], R11 = rr[2];
            float ch = (rowbase + (float)(pix >> 7)) * 0.0078125f;
            float cw = ((float)(pix & 127) + 0.5f) * 0.0078125f;
            a0 += R00;
            a1 += R01;
            a2 += R11;
            a3 += R00 * ch + R01 * cw;
            a4 += R01 * ch + R11 * cw;
        }
        ls_merge[tid][0] = a0;
        ls_merge[tid][1] = a1;
        ls_merge[tid][2] = a2;
        ls_merge[tid][3] = a3;
        ls_merge[tid][4] = a4;
    }
    __syncthreads();

    // ---- merge 3 slices, write transposed block partial ----
    if (tid < NR) {
        float* outp = partial + ((long)(b * NR + tid) * BPB + blockIdx.x) * 5;
#pragma unroll
        for (int f = 0; f < 5; ++f)
            outp[f] = ls_merge[tid * 3 + 0][f] + ls_merge[tid * 3 + 1][f] +
                      ls_merge[tid * 3 + 2][f];
    }
}

// Kernel 2 (round-10 keeper): one wave per (b,cls,pt). 64 lanes read 64
// consecutive 20-B records (coalesced 1280 B), f64 butterfly, 2x2 solve.
__global__ __launch_bounds__(256) void cls_vote_solve(
    const float* __restrict__ partial, float* __restrict__ out)
{
    const int wave = threadIdx.x >> 6;
    const int lane = threadIdx.x & 63;
    const int id = blockIdx.x * 4 + wave;   // (b*72 + r), r = cls*9+pt
    if (id >= Bsz * NR) return;

    const float* pp = partial + ((long)id * BPB + lane) * 5;
    double a  = (double)pp[0];
    double bb = (double)pp[1];
    double c  = (double)pp[2];
    double q0 = (double)pp[3];
    double q1 = (double)pp[4];

#pragma unroll
    for (int off = 1; off < 64; off <<= 1) {
        a  += __shfl_xor(a, off, 64);
        bb += __shfl_xor(bb, off, 64);
        c  += __shfl_xor(c, off, 64);
        q0 += __shfl_xor(q0, off, 64);
        q1 += __shfl_xor(q1, off, 64);
    }

    if (lane == 0) {
        double det = a * c - bb * bb;
        double p0 = 0.0, p1 = 0.0;
        if (det != 0.0) {
            double ia = c / det, ib = -bb / det, ic = a / det;
            p0 = ia * q0 + ib * q1;
            p1 = ib * q0 + ic * q1;
        }
        out[2 * id + 0] = (float)(p0 * 128.0);
        out[2 * id + 1] = (float)(p1 * 128.0);
    }
}

extern "C" void kernel_launch(void* const* d_in, const int* in_sizes, int n_in,
                              void* d_out, int out_size, void* d_ws, size_t ws_size,
                              hipStream_t stream) {
    const float* seg    = (const float*)d_in[0];
    const float* direct = (const float*)d_in[1];
    const float* wts    = (const float*)d_in[2];
    float* out = (float*)d_out;
    float* partial = (float*)d_ws;  // 8*72*64*5*4 = 737,280 B

    dim3 grid1(BPB, Bsz);
    cls_vote_partial<<<grid1, THREADS, 0, stream>>>(seg, direct, wts, partial);

    int nwaves = Bsz * NR;          // 576 waves, 4 per block
    cls_vote_solve<<<nwaves / 4, 256, 0, stream>>>(partial, out);
}